// Round 2
// baseline (67.523 us; speedup 1.0000x reference)
//
#include <hip/hip_runtime.h>
#include <math.h>

// ParametricDrumSynth on MI355X — single fused kernel, R5 (resubmit; R1 run
// died on container acquisition, not kernel behavior).
//
// Harness poison fill (256 MB, ~40 us @ 83% HBM peak) dominates the timed
// window and is not addressable.  This round removes the remaining
// addressable overhead: the second kernel launch, the full-grid drain
// between K1 and K2, and the ws_tr global round-trip.
//
// Fusion is made cheap by recomputing tr[] per tap instead of staging it:
//   tr[k] = sine_tanh(k) + FIR64(noise_t,k) * exp(-20*decay*t_k) * gain/2
// The FIR term's envelope exp(-20*decay*t) is < 1e-7 beyond
// kcut = ln(1e7)/(20*decay) * 23999  (~2420 samples at decay=8), so of the
// <=75 resonator taps (B = 48000/freq_r = 320 on the bench) only ~8 need
// the 64-tap FIR; the rest need only the 4-transcendental sine part.
// Dropped-term error <= 75 * |filtered|max * gain/2 * 1e-7 ~ 4e-5,
// far below the 5.2e-2 threshold.  decay<=0 -> kcut=kN (exact, slow, unbenched).
//
// Integral-delay closed form (bench path, fully parallel):
//   res[i] = sum_{m=0..i/B} fb^m * tr[i-mB]
// split into (A) sine part over all taps, ascending running weight, and
// (B) FIR part over the ~8 taps with k < kcut (exact weight fb^mlo carried
// out of loop A — no powf).  Fractional delay: serial banded fallback in
// block 0 (never taken on bench), tr staged to ws by block 0 itself.

constexpr int   kN    = 24000;
constexpr float kInvT = 1.0f / 23999.0f;   // linspace(0,1,N) step
constexpr int   kBT   = 64;                // block size (1 wave); 375*64 == 24000

// 0.1 * sum_{j=0}^{63} 0.9^j x[k-j]   (one-pole truncated to 64 taps;
// 0.9^64 ~ 1.2e-3, error << threshold).  4x16 Horner chains for ILP.
__device__ __forceinline__ float fir_filtered(const float* __restrict__ x, int k) {
  float p0 = 0.f, p1 = 0.f, p2 = 0.f, p3 = 0.f;
  if (k >= 63) {                           // fast path: no guards
    #pragma unroll
    for (int j = 15; j >= 0; --j) {
      const int b = k - j;
      p0 = fmaf(0.9f, p0, x[b     ]);
      p1 = fmaf(0.9f, p1, x[b - 16]);
      p2 = fmaf(0.9f, p2, x[b - 32]);
      p3 = fmaf(0.9f, p3, x[b - 48]);
    }
  } else {
    #pragma unroll
    for (int j = 15; j >= 0; --j) {
      const int b = k - j;
      p0 = fmaf(0.9f, p0, (b      >= 0) ? x[b     ] : 0.0f);
      p1 = fmaf(0.9f, p1, (b - 16 >= 0) ? x[b - 16] : 0.0f);
      p2 = fmaf(0.9f, p2, (b - 32 >= 0) ? x[b - 32] : 0.0f);
      p3 = fmaf(0.9f, p3, (b - 48 >= 0) ? x[b - 48] : 0.0f);
    }
  }
  return 0.1f * (p0 + 0.185302019f * p1 + 0.034336838f * p2 + 0.006362685f * p3);
}

// tanh(sat * sin(2*pi*f*t) * exp(-decay*t) * gain),  tanh(x) = 1 - 2/(e^{2x}+1)
__device__ __forceinline__ float sine_part(int k, float decay_t, float freq_t,
                                           float sat, float gain_t) {
  const float t = (float)k * kInvT;
  float s = __sinf(6.28318530718f * freq_t * t) * __expf(-decay_t * t) * gain_t;
  const float e2 = __expf(2.0f * sat * s);
  return 1.0f - 2.0f / (e2 + 1.0f);
}

__device__ __forceinline__ float noise_part(const float* __restrict__ noise_t,
                                            int k, float decay_t, float gain_t) {
  return fir_filtered(noise_t, k)
       * __expf(-decay_t * 20.0f * (float)k * kInvT) * (gain_t * 0.5f);
}

__global__ __launch_bounds__(kBT) void k_fused(
    const float* __restrict__ params,
    const float* __restrict__ noise_t,
    const float* __restrict__ noise_n,
    float* __restrict__ ws_tr,        // fallback path only
    float* __restrict__ res_ws,       // fallback path only
    float* __restrict__ out)
{
  const float decay_t = params[1];
  const float freq_t  = params[2];
  const float sat     = params[3];
  const float gain_t  = params[4];
  const float fb      = params[6];
  const float gr      = params[7];
  const float att     = params[8];
  const float dec     = params[9];
  const float gn      = params[10];

  const float Dd = 48000.0f / params[5];   // delay in samples (fp32, as ref)
  const float fD = floorf(Dd);
  const int   B  = (int)fD;

  // FIR-noise cutoff: exp(-20*decay*t_k) < 1e-7 for k >= kcut.
  int kcut = kN;
  if (decay_t > 0.0f) {
    const float kc = 16.118f / (20.0f * decay_t) * 23999.0f;
    kcut = (kc >= (float)kN) ? kN : ((int)kc + 1);
  }

  if (Dd == fD && B >= 1) {
    // -------- integral delay: closed-form, fully parallel, no staging -----
    const int i = blockIdx.x * kBT + threadIdx.x;
    if (i >= kN) return;

    const int Mmax = i / B;                // taps m=0..Mmax have k >= 0
    int mlo = 0;                           // first m with k = i-mB < kcut
    if (i - kcut + 1 > 0) mlo = (i - kcut + B) / B;   // ceil((i-kcut+1)/B)

    // (A) sine/tanh part of every tap, ascending running weight fb^m.
    float s_sum = 0.0f, w = 1.0f, w_lo = 1.0f, s_direct = 0.0f;
    #pragma unroll 4
    for (int m = 0; m <= Mmax; ++m) {
      const int k = i - m * B;
      const float s = sine_part(k, decay_t, freq_t, sat, gain_t);
      if (m == 0)   s_direct = s;          // sine part of tr[i]
      if (m == mlo) w_lo = w;              // exact fb^mlo for loop B
      s_sum = fmaf(w, s, s_sum);
      w *= fb;
    }

    // (B) FIR noise component: only taps with k < kcut contribute (~8 on bench).
    float f_sum = 0.0f, f_direct = 0.0f, wf = w_lo;
    for (int m = mlo; m <= Mmax; ++m) {
      const int k = i - m * B;
      const float f = noise_part(noise_t, k, decay_t, gain_t);
      if (m == 0) f_direct = f;            // FIR part of tr[i] (only if i < kcut)
      f_sum = fmaf(wf, f, f_sum);
      wf *= fb;
    }

    const float tri = s_direct + f_direct; // tr[i]
    const float res = s_sum + f_sum;       // sum fb^m tr[i-mB]  (incl. m=0)
    const float t   = (float)i * kInvT;
    const float env = (1.0f - __expf(-att * t)) * __expf(-dec * t);
    out[i] = tri + noise_n[i] * env * gn + gr * res;
  } else {
    // -------- general fractional delay: serial banded fallback (block 0) --
    if (blockIdx.x != 0) return;
    const int tid = threadIdx.x;

    // Stage tr into ws_tr (block 0 computes it itself now).
    for (int k = tid; k < kN; k += kBT) {
      float v = sine_part(k, decay_t, freq_t, sat, gain_t);
      if (k < kcut) v += noise_part(noise_t, k, decay_t, gain_t);
      ws_tr[k] = v;
    }
    __syncthreads();

    const int Bb = (B < 1) ? 1 : B;
    const int nBands = (kN + Bb - 1) / Bb;
    // res_ws[i] = tr[i] + fb*interp(res_ws)*valid, scan order; unwritten
    // entries read as 0 (reference scan semantics), so no zero-init needed.
    for (int kb = 0; kb < nBands; ++kb) {
      const int start = kb * Bb;
      const int end = (start + Bb < kN) ? (start + Bb) : kN;
      if (tid == 0) {
        const int i = start;
        const float delayed = (float)i - Dd;
        const float validf = (delayed >= 0.0f) ? 1.0f : 0.0f;
        int fl = (int)floorf(delayed);
        fl = fl < 0 ? 0 : (fl > kN - 1 ? kN - 1 : fl);
        const int ce = fl + 1 > kN - 1 ? kN - 1 : fl + 1;
        const float frac = delayed - (float)fl;
        const float vfl = (fl <= start - 1) ? res_ws[fl] : 0.0f;
        const float vce = (ce <= start - 1) ? res_ws[ce] : 0.0f;
        res_ws[i] = ws_tr[i] + fb * ((1.0f - frac) * vfl + frac * vce) * validf;
      }
      __syncthreads();
      for (int i = start + 1 + tid; i < end; i += kBT) {
        const float delayed = (float)i - Dd;
        const float validf = (delayed >= 0.0f) ? 1.0f : 0.0f;
        int fl = (int)floorf(delayed);
        fl = fl < 0 ? 0 : (fl > kN - 1 ? kN - 1 : fl);
        const int ce = fl + 1 > kN - 1 ? kN - 1 : fl + 1;
        const float frac = delayed - (float)fl;
        const float vfl = (fl <= start) ? res_ws[fl] : 0.0f;
        const float vce = (ce <= start) ? res_ws[ce] : 0.0f;
        res_ws[i] = ws_tr[i] + fb * ((1.0f - frac) * vfl + frac * vce) * validf;
      }
      __syncthreads();
    }
    for (int i = tid; i < kN; i += kBT) {
      const float t   = (float)i * kInvT;
      const float env = (1.0f - __expf(-att * t)) * __expf(-dec * t);
      out[i] = ws_tr[i] + noise_n[i] * env * gn + gr * res_ws[i];
    }
  }
}

extern "C" void kernel_launch(void* const* d_in, const int* in_sizes, int n_in,
                              void* d_out, int out_size, void* d_ws, size_t ws_size,
                              hipStream_t stream) {
  const float* params  = (const float*)d_in[0];
  const float* noise_t = (const float*)d_in[1];
  const float* noise_n = (const float*)d_in[2];
  float* out = (float*)d_out;
  float* ws_tr  = (float*)d_ws;            // 24000 floats (fallback only)
  float* ws_res = (float*)d_ws + kN;       // 24000 floats (fallback only)

  const int nb = (kN + kBT - 1) / kBT;     // 375 blocks -> all 256 CUs touched
  k_fused<<<nb, kBT, 0, stream>>>(params, noise_t, noise_n, ws_tr, ws_res, out);
}

// Round 3
// 62.732 us; speedup vs baseline: 1.0764x; 1.0764x over previous
//
#include <hip/hip_runtime.h>
#include <math.h>

// ParametricDrumSynth on MI355X — fully parallel two-kernel form, R6
// (revert to R4: best-measured at 63.2 us).
//
// A/B history: R5 fused single-kernel (recompute tr per tap) measured 67.5 us
// vs this form's 63.2 us.  The fusion's 8x FIR recompute (~512 VMEM
// instructions/wave, no TLP at 1.5 waves/CU) + ~300 quarter-rate
// transcendentals in the tap loop cost about what the saved launch+drain
// bought.  Timed window is dominated by the harness's 256 MB poison fill
// (~40 us @ 83-85% HBM peak) + reset micro-dispatches; our two kernels are
// ~5 us combined and never appear in rocprof top-5.
//
// K1 (375x64): transient -> ws_tr.  One-pole lowpass truncated to 64-tap FIR
//     (0.9^64 ~ 1.2e-3; error << 5.2e-2 threshold), 4x16 ILP Horner chains,
//     fast transcendentals.  Unguarded loads for i >= 63.
// K2 (375x64): resonator in CLOSED FORM.  delay = 48000/freq_r integral
//     (bench: 320.0) -> frac == 0 -> recurrence expands to
//        res[i] = sum_{m=0..i/B} fb^m * tr[i - m*B]   (<= 75 taps)
//     Fully-unrolled JMAX=25 x 3-chain Horner whenever B >= 320 (compile-time
//     trip count: compiler hoists all 75 independent loads -> one latency
//     exposure instead of 25 serialized L2 round-trips).  Taps with i0 < 0
//     contribute exact zeros through the chain, so the unrolled form is valid
//     for ALL B >= 320, not just 320.  Runtime loop for 1 <= B < 320;
//     serial banded fallback for non-integral delay (never taken on bench).

constexpr int   kN    = 24000;
constexpr float kInvT = 1.0f / 23999.0f;   // linspace(0,1,N) step
constexpr int   kBT   = 64;                // block size (1 wave)

// ---------------------------------------------------------------- K1 ------
__global__ __launch_bounds__(kBT) void k1_transient(
    const float* __restrict__ params,
    const float* __restrict__ noise_t,
    float* __restrict__ tr)
{
  const int i = blockIdx.x * kBT + threadIdx.x;
  if (i >= kN) return;

  const float decay_t = params[1];
  const float freq_t  = params[2];
  const float sat     = params[3];
  const float gain_t  = params[4];

  // filtered[i] = 0.1 * sum_{k=0}^{63} 0.9^k x[i-k], 4x16 Horner chains.
  float p0 = 0.f, p1 = 0.f, p2 = 0.f, p3 = 0.f;
  if (i >= 63) {                           // fast path: no guards
    #pragma unroll
    for (int j = 15; j >= 0; --j) {
      const int b = i - j;
      p0 = fmaf(0.9f, p0, noise_t[b     ]);
      p1 = fmaf(0.9f, p1, noise_t[b - 16]);
      p2 = fmaf(0.9f, p2, noise_t[b - 32]);
      p3 = fmaf(0.9f, p3, noise_t[b - 48]);
    }
  } else {
    #pragma unroll
    for (int j = 15; j >= 0; --j) {
      const int b = i - j;
      p0 = fmaf(0.9f, p0, (b      >= 0) ? noise_t[b     ] : 0.0f);
      p1 = fmaf(0.9f, p1, (b - 16 >= 0) ? noise_t[b - 16] : 0.0f);
      p2 = fmaf(0.9f, p2, (b - 32 >= 0) ? noise_t[b - 32] : 0.0f);
      p3 = fmaf(0.9f, p3, (b - 48 >= 0) ? noise_t[b - 48] : 0.0f);
    }
  }
  const float filtered = 0.1f * (p0 + 0.185302019f * p1
                                    + 0.034336838f * p2
                                    + 0.006362685f * p3);

  const float t = (float)i * kInvT;
  float s = __sinf(6.28318530718f * freq_t * t) * __expf(-decay_t * t) * gain_t;
  // tanh(sat*s) = 1 - 2/(exp(2*sat*s)+1)
  const float e2 = __expf(2.0f * sat * s);
  s = 1.0f - 2.0f / (e2 + 1.0f);
  const float nc = filtered * __expf(-decay_t * 20.0f * t) * (gain_t * 0.5f);
  tr[i] = s + nc;
}

// ---------------------------------------------------------------- K2 ------
__global__ __launch_bounds__(kBT) void k2_combine(
    const float* __restrict__ params,
    const float* __restrict__ noise_n,
    const float* __restrict__ tr,     // ws_tr (from K1)
    float* __restrict__ res_ws,       // scratch for fallback path only
    float* __restrict__ out)
{
  const float fb  = params[6];
  const float gr  = params[7];
  const float att = params[8];
  const float dec = params[9];
  const float gn  = params[10];

  const float Dd = 48000.0f / params[5];   // delay in samples (fp32, as ref)
  const float fD = floorf(Dd);
  const int   B  = (int)fD;

  if (Dd == fD && B >= 1) {
    // -------- integral delay: closed-form convolution, fully parallel -----
    const int i = blockIdx.x * kBT + threadIdx.x;
    if (i >= kN) return;

    const float fb3 = fb * fb * fb;
    float res;

    if (B >= 320) {
      // Mmax <= 74 -> JMAX = 25 covers every tap; compile-time unroll.
      float p0 = 0.f, p1 = 0.f, p2 = 0.f;
      #pragma unroll
      for (int j = 24; j >= 0; --j) {      // high m first: invalid taps add 0
        const int i0 = i - 3 * j * B;      // tap m = 3j
        const int i1 = i0 - B;             // tap m = 3j+1
        const int i2 = i1 - B;             // tap m = 3j+2
        p0 = fmaf(fb3, p0, (i0 >= 0) ? tr[i0] : 0.0f);
        p1 = fmaf(fb3, p1, (i1 >= 0) ? tr[i1] : 0.0f);
        p2 = fmaf(fb3, p2, (i2 >= 0) ? tr[i2] : 0.0f);
      }
      res = p0 + fb * p1 + (fb * fb) * p2; // includes m=0 (= tr[i])
    } else {
      // small-delay integral case (not the bench): runtime trip count.
      const int Mmax = (kN - 1) / B;
      const int J    = Mmax / 3 + 1;
      float p0 = 0.f, p1 = 0.f, p2 = 0.f;
      for (int j = J - 1; j >= 0; --j) {
        const int i0 = i - 3 * j * B;
        const int i1 = i0 - B;
        const int i2 = i1 - B;
        p0 = fmaf(fb3, p0, (i0 >= 0) ? tr[i0] : 0.0f);
        p1 = fmaf(fb3, p1, (i1 >= 0) ? tr[i1] : 0.0f);
        p2 = fmaf(fb3, p2, (i2 >= 0) ? tr[i2] : 0.0f);
      }
      res = p0 + fb * p1 + (fb * fb) * p2;
    }

    const float t   = (float)i * kInvT;
    const float env = (1.0f - __expf(-att * t)) * __expf(-dec * t);
    out[i] = tr[i] + noise_n[i] * env * gn + gr * res;
  } else {
    // -------- general fractional delay: serial banded fallback (block 0) --
    if (blockIdx.x != 0) return;
    const int tid = threadIdx.x;
    const int Bb = (B < 1) ? 1 : B;
    const int nBands = (kN + Bb - 1) / Bb;
    // res_ws[i] = tr[i] + fb*interp(res_ws)*valid, scan order; unwritten
    // entries read as 0 (reference scan semantics), so no zero-init needed.
    for (int k = 0; k < nBands; ++k) {
      const int start = k * Bb;
      const int end = (start + Bb < kN) ? (start + Bb) : kN;
      if (tid == 0) {
        const int i = start;
        const float delayed = (float)i - Dd;
        const float validf = (delayed >= 0.0f) ? 1.0f : 0.0f;
        int fl = (int)floorf(delayed);
        fl = fl < 0 ? 0 : (fl > kN - 1 ? kN - 1 : fl);
        const int ce = fl + 1 > kN - 1 ? kN - 1 : fl + 1;
        const float frac = delayed - (float)fl;
        const float vfl = (fl <= start - 1) ? res_ws[fl] : 0.0f;
        const float vce = (ce <= start - 1) ? res_ws[ce] : 0.0f;
        res_ws[i] = tr[i] + fb * ((1.0f - frac) * vfl + frac * vce) * validf;
      }
      __syncthreads();
      for (int i = start + 1 + tid; i < end; i += kBT) {
        const float delayed = (float)i - Dd;
        const float validf = (delayed >= 0.0f) ? 1.0f : 0.0f;
        int fl = (int)floorf(delayed);
        fl = fl < 0 ? 0 : (fl > kN - 1 ? kN - 1 : fl);
        const int ce = fl + 1 > kN - 1 ? kN - 1 : fl + 1;
        const float frac = delayed - (float)fl;
        const float vfl = (fl <= start) ? res_ws[fl] : 0.0f;
        const float vce = (ce <= start) ? res_ws[ce] : 0.0f;
        res_ws[i] = tr[i] + fb * ((1.0f - frac) * vfl + frac * vce) * validf;
      }
      __syncthreads();
    }
    for (int i = tid; i < kN; i += kBT) {
      const float t   = (float)i * kInvT;
      const float env = (1.0f - __expf(-att * t)) * __expf(-dec * t);
      out[i] = tr[i] + noise_n[i] * env * gn + gr * res_ws[i];
    }
  }
}

extern "C" void kernel_launch(void* const* d_in, const int* in_sizes, int n_in,
                              void* d_out, int out_size, void* d_ws, size_t ws_size,
                              hipStream_t stream) {
  const float* params  = (const float*)d_in[0];
  const float* noise_t = (const float*)d_in[1];
  const float* noise_n = (const float*)d_in[2];
  float* out = (float*)d_out;
  float* ws_tr  = (float*)d_ws;            // 24000 floats
  float* ws_res = (float*)d_ws + kN;       // 24000 floats (fallback only)

  const int nb = (kN + kBT - 1) / kBT;     // 375 blocks -> all 256 CUs touched
  k1_transient<<<nb, kBT, 0, stream>>>(params, noise_t, ws_tr);
  k2_combine<<<nb, kBT, 0, stream>>>(params, noise_n, ws_tr, ws_res, out);
}